// Round 1
// baseline (537.348 us; speedup 1.0000x reference)
//
#include <hip/hip_runtime.h>

#define N_NODES 50000
#define N_EDGES 600000
#define F_IN 128
#define H1 64
#define H2 32

// ---------------------------------------------------------------------------
// Fold the two linear layers of each GIN MLP into one matrix + bias:
//   M1[f][h] = sum_m w1a[m][f] * w1b[h][m]   (128x64)
//   c1[h]    = sum_m b1a[m] * w1b[h][m] + b1b[h]
//   M2[h][o] = sum_m w2a[m][h] * w2b[o][m]   (64x32)
//   c2[o]    = sum_m b2a[m] * w2b[o][m] + b2b[o]
// ---------------------------------------------------------------------------
__global__ __launch_bounds__(256) void prep_weights(
    const float* __restrict__ w1a, const float* __restrict__ b1a,
    const float* __restrict__ w1b, const float* __restrict__ b1b,
    const float* __restrict__ w2a, const float* __restrict__ b2a,
    const float* __restrict__ w2b, const float* __restrict__ b2b,
    float* __restrict__ M1, float* __restrict__ c1,
    float* __restrict__ M2, float* __restrict__ c2) {
  int tid = threadIdx.x;
  for (int i = tid; i < F_IN * H1; i += 256) {
    int f = i >> 6, h = i & 63;
    float s = 0.f;
    for (int m = 0; m < H1; ++m) s += w1a[m * F_IN + f] * w1b[h * H1 + m];
    M1[i] = s;
  }
  for (int i = tid; i < H1; i += 256) {
    float s = b1b[i];
    for (int m = 0; m < H1; ++m) s += b1a[m] * w1b[i * H1 + m];
    c1[i] = s;
  }
  for (int i = tid; i < H1 * H2; i += 256) {
    int h = i >> 5, o = i & 31;
    float s = 0.f;
    for (int m = 0; m < H2; ++m) s += w2a[m * H1 + h] * w2b[o * H2 + m];
    M2[i] = s;
  }
  for (int i = tid; i < H2; i += 256) {
    float s = b2b[i];
    for (int m = 0; m < H2; ++m) s += b2a[m] * w2b[i * H2 + m];
    c2[i] = s;
  }
}

// y = x @ M1   (N x 128) @ (128 x 64) -> (N x 64)
__global__ __launch_bounds__(256) void gemm1(
    const float* __restrict__ x, const float* __restrict__ M1,
    float* __restrict__ y) {
  __shared__ float sW[F_IN * H1];  // 32 KiB
  int tid = threadIdx.x;
  for (int i = tid; i < F_IN * H1; i += 256) sW[i] = M1[i];
  __syncthreads();
  int col = tid & 63;
  int rg  = tid >> 6;  // 0..3
  int base = blockIdx.x * 32;
  for (int i = 0; i < 8; ++i) {
    int row = base + rg * 8 + i;
    if (row < N_NODES) {
      const float* xr = x + (long long)row * F_IN;
      float acc = 0.f;
#pragma unroll
      for (int k0 = 0; k0 < F_IN; k0 += 4) {
        float4 xv = *reinterpret_cast<const float4*>(xr + k0);
        acc += xv.x * sW[(k0 + 0) * H1 + col];
        acc += xv.y * sW[(k0 + 1) * H1 + col];
        acc += xv.z * sW[(k0 + 2) * H1 + col];
        acc += xv.w * sW[(k0 + 3) * H1 + col];
      }
      y[(long long)row * H1 + col] = acc;
    }
  }
}

// agg1[dst] += y[src]   (64 floats per edge, thread per (edge, feature))
__global__ __launch_bounds__(256) void scatter1(
    const int* __restrict__ ei, const float* __restrict__ y,
    float* __restrict__ agg) {
  int idx = blockIdx.x * 256 + threadIdx.x;
  int e = idx >> 6;
  if (e >= N_EDGES) return;
  int f = idx & 63;
  int s = ei[e];
  int d = ei[N_EDGES + e];
  atomicAdd(&agg[(long long)d * H1 + f], y[(long long)s * H1 + f]);
}

// z = relu((1+eps1)*y + agg1 + c1) @ M2    (N x 64) -> (N x 32)
__global__ __launch_bounds__(256) void gemm2(
    const float* __restrict__ y, const float* __restrict__ agg1,
    const float* __restrict__ M2, const float* __restrict__ c1,
    const float* __restrict__ eps1p, float* __restrict__ z) {
  __shared__ float sW[H1 * H2];  // 8 KiB
  __shared__ float sc1[H1];
  int tid = threadIdx.x;
  for (int i = tid; i < H1 * H2; i += 256) sW[i] = M2[i];
  if (tid < H1) sc1[tid] = c1[tid];
  __syncthreads();
  float eps1 = 1.0f + *eps1p;
  int col = tid & 31;
  int rg  = tid >> 5;  // 0..7
  int base = blockIdx.x * 32;
  for (int i = 0; i < 4; ++i) {
    int row = base + rg * 4 + i;
    if (row < N_NODES) {
      const float* yr = y + (long long)row * H1;
      const float* ar = agg1 + (long long)row * H1;
      float acc = 0.f;
#pragma unroll
      for (int k = 0; k < H1; ++k) {
        float h = fmaxf(eps1 * yr[k] + ar[k] + sc1[k], 0.f);
        acc += h * sW[k * H2 + col];
      }
      z[(long long)row * H2 + col] = acc;
    }
  }
}

// agg2[dst] += z[src]   (32 floats per edge)
__global__ __launch_bounds__(256) void scatter2(
    const int* __restrict__ ei, const float* __restrict__ z,
    float* __restrict__ agg) {
  int idx = blockIdx.x * 256 + threadIdx.x;
  int e = idx >> 5;
  if (e >= N_EDGES) return;
  int f = idx & 31;
  int s = ei[e];
  int d = ei[N_EDGES + e];
  atomicAdd(&agg[(long long)d * H2 + f], z[(long long)s * H2 + f]);
}

// h2 = relu((1+eps2)*z + agg2 + c2);  p = dot(h2, wl);  r = dot(h2, wr)
__global__ __launch_bounds__(256) void node_reduce(
    const float* __restrict__ z, const float* __restrict__ agg2,
    const float* __restrict__ c2, const float* __restrict__ eps2p,
    const float* __restrict__ wl, const float* __restrict__ wr,
    float* __restrict__ p, float* __restrict__ r) {
  int idx = blockIdx.x * 256 + threadIdx.x;
  int node = idx >> 5;
  if (node >= N_NODES) return;
  int f = idx & 31;
  float eps2 = 1.0f + *eps2p;
  float h = fmaxf(eps2 * z[(long long)node * H2 + f] +
                      agg2[(long long)node * H2 + f] + c2[f],
                  0.f);
  float pd = h * wl[f];
  float rd = h * wr[f];
#pragma unroll
  for (int m = 16; m >= 1; m >>= 1) {
    pd += __shfl_xor(pd, m, 32);
    rd += __shfl_xor(rd, m, 32);
  }
  if (f == 0) {
    p[node] = pd;
    r[node] = rd;
  }
}

// num[dst] += ew * p[src];  cnt[dst] += 1
__global__ __launch_bounds__(256) void edge_scalar(
    const int* __restrict__ ei, const float* __restrict__ ea,
    const float* __restrict__ p, float* __restrict__ num,
    float* __restrict__ cnt) {
  int e = blockIdx.x * 256 + threadIdx.x;
  if (e >= N_EDGES) return;
  int s = ei[e];
  int d = ei[N_EDGES + e];
  atomicAdd(&num[d], ea[e] * p[s]);
  atomicAdd(&cnt[d], 1.0f);
}

// out = relu(num / max(cnt,1) + bl + r)
__global__ __launch_bounds__(256) void finalize(
    const float* __restrict__ num, const float* __restrict__ cnt,
    const float* __restrict__ r, const float* __restrict__ blp,
    float* __restrict__ out) {
  int i = blockIdx.x * 256 + threadIdx.x;
  if (i >= N_NODES) return;
  float mean = num[i] / fmaxf(cnt[i], 1.0f);
  out[i] = fmaxf(mean + blp[0] + r[i], 0.f);
}

extern "C" void kernel_launch(void* const* d_in, const int* in_sizes, int n_in,
                              void* d_out, int out_size, void* d_ws,
                              size_t ws_size, hipStream_t stream) {
  const float* x   = (const float*)d_in[0];
  const int*   ei  = (const int*)d_in[1];
  const float* ea  = (const float*)d_in[2];
  const float* w1a = (const float*)d_in[3];
  const float* b1a = (const float*)d_in[4];
  const float* w1b = (const float*)d_in[5];
  const float* b1b = (const float*)d_in[6];
  const float* eps1 = (const float*)d_in[7];
  const float* w2a = (const float*)d_in[8];
  const float* b2a = (const float*)d_in[9];
  const float* w2b = (const float*)d_in[10];
  const float* b2b = (const float*)d_in[11];
  const float* eps2 = (const float*)d_in[12];
  const float* wl  = (const float*)d_in[13];
  const float* bl  = (const float*)d_in[14];
  const float* wr  = (const float*)d_in[15];
  float* out = (float*)d_out;

  // workspace layout (floats)
  float* ws = (float*)d_ws;
  float* M1   = ws;                       // 8192
  float* c1   = M1 + F_IN * H1;           // 64
  float* M2   = c1 + H1;                  // 2048
  float* c2   = M2 + H1 * H2;             // 32
  float* y    = c2 + H2;                  // N*64
  float* agg1 = y + (long long)N_NODES * H1;     // N*64
  float* z    = agg1 + (long long)N_NODES * H1;  // N*32
  float* agg2 = z + (long long)N_NODES * H2;     // N*32
  float* p    = agg2 + (long long)N_NODES * H2;  // N
  float* r    = p + N_NODES;              // N
  float* num  = r + N_NODES;              // N
  float* cnt  = num + N_NODES;            // N

  // zero the accumulators (ws is poisoned before every launch)
  hipMemsetAsync(agg1, 0, sizeof(float) * (size_t)N_NODES * H1, stream);
  hipMemsetAsync(agg2, 0, sizeof(float) * (size_t)N_NODES * H2, stream);
  hipMemsetAsync(num, 0, sizeof(float) * (size_t)N_NODES, stream);
  hipMemsetAsync(cnt, 0, sizeof(float) * (size_t)N_NODES, stream);

  prep_weights<<<1, 256, 0, stream>>>(w1a, b1a, w1b, b1b, w2a, b2a, w2b, b2b,
                                      M1, c1, M2, c2);

  gemm1<<<(N_NODES + 31) / 32, 256, 0, stream>>>(x, M1, y);

  scatter1<<<(N_EDGES * 64) / 256, 256, 0, stream>>>(ei, y, agg1);

  gemm2<<<(N_NODES + 31) / 32, 256, 0, stream>>>(y, agg1, M2, c1, eps1, z);

  scatter2<<<(N_EDGES * 32) / 256, 256, 0, stream>>>(ei, z, agg2);

  node_reduce<<<(N_NODES * 32 + 255) / 256, 256, 0, stream>>>(
      z, agg2, c2, eps2, wl, wr, p, r);

  edge_scalar<<<(N_EDGES + 255) / 256, 256, 0, stream>>>(ei, ea, p, num, cnt);

  finalize<<<(N_NODES + 255) / 256, 256, 0, stream>>>(num, cnt, r, bl, out);
}

// Round 2
// 532.800 us; speedup vs baseline: 1.0085x; 1.0085x over previous
//
#include <hip/hip_runtime.h>

#define N_NODES 50000
#define N_EDGES 600000
#define F_IN 128
#define H1 64
#define H2 32

// ---------------------------------------------------------------------------
// Fold each GIN MLP (two linears, no inner activation) into one matrix+bias.
// ---------------------------------------------------------------------------
__global__ __launch_bounds__(256) void prep_weights(
    const float* __restrict__ w1a, const float* __restrict__ b1a,
    const float* __restrict__ w1b, const float* __restrict__ b1b,
    const float* __restrict__ w2a, const float* __restrict__ b2a,
    const float* __restrict__ w2b, const float* __restrict__ b2b,
    float* __restrict__ M1, float* __restrict__ c1,
    float* __restrict__ M2, float* __restrict__ c2) {
  int tid = threadIdx.x;
  for (int i = tid; i < F_IN * H1; i += 256) {
    int f = i >> 6, h = i & 63;
    float s = 0.f;
    for (int m = 0; m < H1; ++m) s += w1a[m * F_IN + f] * w1b[h * H1 + m];
    M1[i] = s;
  }
  for (int i = tid; i < H1; i += 256) {
    float s = b1b[i];
    for (int m = 0; m < H1; ++m) s += b1a[m] * w1b[i * H1 + m];
    c1[i] = s;
  }
  for (int i = tid; i < H1 * H2; i += 256) {
    int h = i >> 5, o = i & 31;
    float s = 0.f;
    for (int m = 0; m < H2; ++m) s += w2a[m * H1 + h] * w2b[o * H2 + m];
    M2[i] = s;
  }
  for (int i = tid; i < H2; i += 256) {
    float s = b2b[i];
    for (int m = 0; m < H2; ++m) s += b2a[m] * w2b[i * H2 + m];
    c2[i] = s;
  }
}

// -------------------- CSR build (by destination) ---------------------------
__global__ __launch_bounds__(256) void count_edges(const int* __restrict__ ei,
                                                   int* __restrict__ counts) {
  int e = blockIdx.x * 256 + threadIdx.x;
  if (e >= N_EDGES) return;
  atomicAdd(&counts[ei[N_EDGES + e]], 1);
}

// single-block exclusive scan of counts -> row_ptr (and cursor copy)
__global__ __launch_bounds__(1024) void scan_counts(const int* __restrict__ counts,
                                                    int* __restrict__ row_ptr,
                                                    int* __restrict__ cursor) {
  __shared__ int ls[1024];
  int t = threadIdx.x;
  const int CH = (N_NODES + 1023) / 1024;  // 49
  int base = t * CH;
  int s = 0;
  for (int i = 0; i < CH; ++i) {
    int j = base + i;
    if (j < N_NODES) s += counts[j];
  }
  ls[t] = s;
  __syncthreads();
  for (int off = 1; off < 1024; off <<= 1) {
    int v = (t >= off) ? ls[t - off] : 0;
    __syncthreads();
    ls[t] += v;
    __syncthreads();
  }
  int run = (t == 0) ? 0 : ls[t - 1];
  for (int i = 0; i < CH; ++i) {
    int j = base + i;
    if (j < N_NODES) {
      row_ptr[j] = run;
      cursor[j] = run;
      run += counts[j];
    }
  }
  if (t == 1023) row_ptr[N_NODES] = ls[1023];
}

__global__ __launch_bounds__(256) void fill_csr(const int* __restrict__ ei,
                                                const float* __restrict__ ea,
                                                int* __restrict__ cursor,
                                                int* __restrict__ csr_src,
                                                float* __restrict__ csr_w) {
  int e = blockIdx.x * 256 + threadIdx.x;
  if (e >= N_EDGES) return;
  int s = ei[e];
  int d = ei[N_EDGES + e];
  int pos = atomicAdd(&cursor[d], 1);
  csr_src[pos] = s;
  csr_w[pos] = ea[e];
}

// -------------------- y = x @ M1  (N x 128 -> N x 64) ----------------------
__global__ __launch_bounds__(256) void gemm1(const float* __restrict__ x,
                                             const float* __restrict__ M1,
                                             float* __restrict__ y) {
  __shared__ float sW[F_IN * H1];  // 32 KiB
  int tid = threadIdx.x;
  for (int i = tid; i < F_IN * H1; i += 256) sW[i] = M1[i];
  __syncthreads();
  int col = tid & 63;
  int rg = tid >> 6;  // 0..3
  int base = blockIdx.x * 32;
  for (int i = 0; i < 8; ++i) {
    int row = base + rg * 8 + i;
    if (row < N_NODES) {
      const float* xr = x + (long long)row * F_IN;
      float acc = 0.f;
#pragma unroll
      for (int k0 = 0; k0 < F_IN; k0 += 4) {
        float4 xv = *reinterpret_cast<const float4*>(xr + k0);
        acc += xv.x * sW[(k0 + 0) * H1 + col];
        acc += xv.y * sW[(k0 + 1) * H1 + col];
        acc += xv.z * sW[(k0 + 2) * H1 + col];
        acc += xv.w * sW[(k0 + 3) * H1 + col];
      }
      y[(long long)row * H1 + col] = acc;
    }
  }
}

// ------ fused: agg1 = gather(y), h = relu((1+e1)y+agg1+c1), z = h @ M2 -----
// one wave (64 lanes) per node; 4 nodes per 256-thread block
__global__ __launch_bounds__(256) void gin2_fused(
    const float* __restrict__ y, const int* __restrict__ row_ptr,
    const int* __restrict__ csr_src, const float* __restrict__ M2,
    const float* __restrict__ c1, const float* __restrict__ eps1p,
    float* __restrict__ z) {
  __shared__ float sM2[H1 * H2];  // 8 KiB
  __shared__ float sc1[H1];
  __shared__ float sh[4][H1];
  int tid = threadIdx.x;
  for (int i = tid; i < H1 * H2; i += 256) sM2[i] = M2[i];
  if (tid < H1) sc1[tid] = c1[tid];
  __syncthreads();
  int wave = tid >> 6, lane = tid & 63;
  int node = blockIdx.x * 4 + wave;
  float eps1 = 1.0f + *eps1p;
  float h = 0.f;
  if (node < N_NODES) {
    int start = row_ptr[node], end = row_ptr[node + 1];
    float agg = 0.f;
    for (int e = start; e < end; ++e) {
      int s = csr_src[e];
      agg += y[(long long)s * H1 + lane];
    }
    h = fmaxf(eps1 * y[(long long)node * H1 + lane] + agg + sc1[lane], 0.f);
  }
  sh[wave][lane] = h;
  __syncthreads();
  if (node < N_NODES) {
    int o = lane & 31, half = lane >> 5;
    float acc = 0.f;
#pragma unroll
    for (int k = 0; k < 32; ++k) {
      int kk = half * 32 + k;
      acc += sh[wave][kk] * sM2[kk * H2 + o];
    }
    acc += __shfl_xor(acc, 32);
    if (half == 0) z[(long long)node * H2 + o] = acc;
  }
}

// -- fused: agg2 = gather(z), h2 = relu((1+e2)z+agg2+c2), p=h2.wl, r=h2.wr --
// 32 lanes per node; 8 nodes per 256-thread block
__global__ __launch_bounds__(256) void gin3_fused(
    const float* __restrict__ z, const int* __restrict__ row_ptr,
    const int* __restrict__ csr_src, const float* __restrict__ c2,
    const float* __restrict__ eps2p, const float* __restrict__ wl,
    const float* __restrict__ wr, float* __restrict__ p,
    float* __restrict__ r) {
  int idx = blockIdx.x * 256 + threadIdx.x;
  int node = idx >> 5;
  if (node >= N_NODES) return;
  int f = idx & 31;
  int start = row_ptr[node], end = row_ptr[node + 1];
  float agg = 0.f;
  for (int e = start; e < end; ++e) {
    int s = csr_src[e];
    agg += z[(long long)s * H2 + f];
  }
  float eps2 = 1.0f + *eps2p;
  float h = fmaxf(eps2 * z[(long long)node * H2 + f] + agg + c2[f], 0.f);
  float pd = h * wl[f];
  float rd = h * wr[f];
#pragma unroll
  for (int m = 16; m >= 1; m >>= 1) {
    pd += __shfl_xor(pd, m, 32);
    rd += __shfl_xor(rd, m, 32);
  }
  if (f == 0) {
    p[node] = pd;
    r[node] = rd;
  }
}

// ---- SAGE: mean of ew*p[src] over in-edges + root path, relu, write out ---
// 16 lanes per node; 16 nodes per 256-thread block
__global__ __launch_bounds__(256) void sage_out(
    const int* __restrict__ row_ptr, const int* __restrict__ csr_src,
    const float* __restrict__ csr_w, const float* __restrict__ p,
    const float* __restrict__ r, const float* __restrict__ blp,
    float* __restrict__ out) {
  int idx = blockIdx.x * 256 + threadIdx.x;
  int node = idx >> 4;
  if (node >= N_NODES) return;
  int l = idx & 15;
  int start = row_ptr[node], end = row_ptr[node + 1];
  float acc = 0.f;
  for (int e = start + l; e < end; e += 16) acc += csr_w[e] * p[csr_src[e]];
#pragma unroll
  for (int m = 8; m >= 1; m >>= 1) acc += __shfl_xor(acc, m, 16);
  if (l == 0) {
    float mean = acc / fmaxf((float)(end - start), 1.0f);
    out[node] = fmaxf(mean + blp[0] + r[node], 0.f);
  }
}

extern "C" void kernel_launch(void* const* d_in, const int* in_sizes, int n_in,
                              void* d_out, int out_size, void* d_ws,
                              size_t ws_size, hipStream_t stream) {
  const float* x = (const float*)d_in[0];
  const int* ei = (const int*)d_in[1];
  const float* ea = (const float*)d_in[2];
  const float* w1a = (const float*)d_in[3];
  const float* b1a = (const float*)d_in[4];
  const float* w1b = (const float*)d_in[5];
  const float* b1b = (const float*)d_in[6];
  const float* eps1 = (const float*)d_in[7];
  const float* w2a = (const float*)d_in[8];
  const float* b2a = (const float*)d_in[9];
  const float* w2b = (const float*)d_in[10];
  const float* b2b = (const float*)d_in[11];
  const float* eps2 = (const float*)d_in[12];
  const float* wl = (const float*)d_in[13];
  const float* bl = (const float*)d_in[14];
  const float* wr = (const float*)d_in[15];
  float* out = (float*)d_out;

  // workspace layout
  float* ws = (float*)d_ws;
  float* M1 = ws;                              // 8192
  float* c1 = M1 + F_IN * H1;                  // 64
  float* M2 = c1 + H1;                         // 2048
  float* c2 = M2 + H1 * H2;                    // 32
  float* y = c2 + H2;                          // N*64
  float* z = y + (long long)N_NODES * H1;      // N*32
  float* p = z + (long long)N_NODES * H2;      // N
  float* r = p + N_NODES;                      // N
  float* csr_w = r + N_NODES;                  // E
  int* counts = (int*)(csr_w + N_EDGES);       // N
  int* cursor = counts + N_NODES;              // N
  int* row_ptr = cursor + N_NODES;             // N+1
  int* csr_src = row_ptr + N_NODES + 1;        // E

  hipMemsetAsync(counts, 0, sizeof(int) * (size_t)N_NODES, stream);

  prep_weights<<<1, 256, 0, stream>>>(w1a, b1a, w1b, b1b, w2a, b2a, w2b, b2b,
                                      M1, c1, M2, c2);

  count_edges<<<(N_EDGES + 255) / 256, 256, 0, stream>>>(ei, counts);
  scan_counts<<<1, 1024, 0, stream>>>(counts, row_ptr, cursor);
  fill_csr<<<(N_EDGES + 255) / 256, 256, 0, stream>>>(ei, ea, cursor, csr_src,
                                                      csr_w);

  gemm1<<<(N_NODES + 31) / 32, 256, 0, stream>>>(x, M1, y);

  gin2_fused<<<(N_NODES + 3) / 4, 256, 0, stream>>>(y, row_ptr, csr_src, M2,
                                                    c1, eps1, z);

  gin3_fused<<<(N_NODES * 32 + 255) / 256, 256, 0, stream>>>(
      z, row_ptr, csr_src, c2, eps2, wl, wr, p, r);

  sage_out<<<(N_NODES * 16 + 255) / 256, 256, 0, stream>>>(row_ptr, csr_src,
                                                           csr_w, p, r, bl, out);
}

// Round 3
// 341.497 us; speedup vs baseline: 1.5735x; 1.5602x over previous
//
#include <hip/hip_runtime.h>

#define N_NODES 50000
#define N_EDGES 600000
#define F_IN 128
#define H1 64
#define H2 32
#define NBLK ((N_NODES + 255) / 256)  // 196 scan blocks

// ---------------------------------------------------------------------------
// Fold each GIN MLP (two linears, no inner activation) into one matrix+bias.
// One thread per output element, parallel across blocks.
// total elements: 8192 (M1) + 64 (c1) + 2048 (M2) + 32 (c2) = 10336
// ---------------------------------------------------------------------------
__global__ __launch_bounds__(256) void prep_weights(
    const float* __restrict__ w1a, const float* __restrict__ b1a,
    const float* __restrict__ w1b, const float* __restrict__ b1b,
    const float* __restrict__ w2a, const float* __restrict__ b2a,
    const float* __restrict__ w2b, const float* __restrict__ b2b,
    float* __restrict__ M1, float* __restrict__ c1,
    float* __restrict__ M2, float* __restrict__ c2) {
  int i = blockIdx.x * 256 + threadIdx.x;
  if (i < F_IN * H1) {
    int f = i >> 6, h = i & 63;
    float s = 0.f;
    for (int m = 0; m < H1; ++m) s += w1a[m * F_IN + f] * w1b[h * H1 + m];
    M1[i] = s;
    return;
  }
  i -= F_IN * H1;
  if (i < H1) {
    float s = b1b[i];
    for (int m = 0; m < H1; ++m) s += b1a[m] * w1b[i * H1 + m];
    c1[i] = s;
    return;
  }
  i -= H1;
  if (i < H1 * H2) {
    int h = i >> 5, o = i & 31;
    float s = 0.f;
    for (int m = 0; m < H2; ++m) s += w2a[m * H1 + h] * w2b[o * H2 + m];
    M2[i] = s;
    return;
  }
  i -= H1 * H2;
  if (i < H2) {
    float s = b2b[i];
    for (int m = 0; m < H2; ++m) s += b2a[m] * w2b[i * H2 + m];
    c2[i] = s;
  }
}

// -------------------- CSR build (by destination) ---------------------------
__global__ __launch_bounds__(256) void count_edges(const int* __restrict__ ei,
                                                   int* __restrict__ counts) {
  int e = blockIdx.x * 256 + threadIdx.x;
  if (e >= N_EDGES) return;
  atomicAdd(&counts[ei[N_EDGES + e]], 1);
}

// phase 1: per-block sums of counts
__global__ __launch_bounds__(256) void block_sums(const int* __restrict__ counts,
                                                  int* __restrict__ bsums) {
  __shared__ int s[256];
  int t = threadIdx.x;
  int i = blockIdx.x * 256 + t;
  s[t] = (i < N_NODES) ? counts[i] : 0;
  __syncthreads();
  for (int off = 128; off > 0; off >>= 1) {
    if (t < off) s[t] += s[t + off];
    __syncthreads();
  }
  if (t == 0) bsums[blockIdx.x] = s[0];
}

// phase 2: exclusive scan of the block sums (NBLK <= 256), one block
__global__ __launch_bounds__(256) void scan_bsums(const int* __restrict__ bsums,
                                                  int* __restrict__ boffs,
                                                  int* __restrict__ row_ptr) {
  __shared__ int s[256];
  int t = threadIdx.x;
  int v = (t < NBLK) ? bsums[t] : 0;
  s[t] = v;
  __syncthreads();
  for (int off = 1; off < 256; off <<= 1) {
    int u = (t >= off) ? s[t - off] : 0;
    __syncthreads();
    s[t] += u;
    __syncthreads();
  }
  if (t < NBLK) boffs[t] = s[t] - v;
  if (t == 255) row_ptr[N_NODES] = s[255];
}

// phase 3: in-block exclusive scan + block offset -> row_ptr, cursor
__global__ __launch_bounds__(256) void emit_rowptr(const int* __restrict__ counts,
                                                   const int* __restrict__ boffs,
                                                   int* __restrict__ row_ptr,
                                                   int* __restrict__ cursor) {
  __shared__ int s[256];
  int t = threadIdx.x;
  int i = blockIdx.x * 256 + t;
  int v = (i < N_NODES) ? counts[i] : 0;
  s[t] = v;
  __syncthreads();
  for (int off = 1; off < 256; off <<= 1) {
    int u = (t >= off) ? s[t - off] : 0;
    __syncthreads();
    s[t] += u;
    __syncthreads();
  }
  if (i < N_NODES) {
    int ex = boffs[blockIdx.x] + s[t] - v;
    row_ptr[i] = ex;
    cursor[i] = ex;
  }
}

__global__ __launch_bounds__(256) void fill_csr(const int* __restrict__ ei,
                                                const float* __restrict__ ea,
                                                int* __restrict__ cursor,
                                                int* __restrict__ csr_src,
                                                float* __restrict__ csr_w) {
  int e = blockIdx.x * 256 + threadIdx.x;
  if (e >= N_EDGES) return;
  int s = ei[e];
  int d = ei[N_EDGES + e];
  int pos = atomicAdd(&cursor[d], 1);
  csr_src[pos] = s;
  csr_w[pos] = ea[e];
}

// -------------------- y = x @ M1  (N x 128 -> N x 64) ----------------------
__global__ __launch_bounds__(256) void gemm1(const float* __restrict__ x,
                                             const float* __restrict__ M1,
                                             float* __restrict__ y) {
  __shared__ float sW[F_IN * H1];  // 32 KiB
  int tid = threadIdx.x;
  for (int i = tid; i < F_IN * H1; i += 256) sW[i] = M1[i];
  __syncthreads();
  int col = tid & 63;
  int rg = tid >> 6;  // 0..3
  int base = blockIdx.x * 32;
  for (int i = 0; i < 8; ++i) {
    int row = base + rg * 8 + i;
    if (row < N_NODES) {
      const float* xr = x + (long long)row * F_IN;
      float acc = 0.f;
#pragma unroll
      for (int k0 = 0; k0 < F_IN; k0 += 4) {
        float4 xv = *reinterpret_cast<const float4*>(xr + k0);
        acc += xv.x * sW[(k0 + 0) * H1 + col];
        acc += xv.y * sW[(k0 + 1) * H1 + col];
        acc += xv.z * sW[(k0 + 2) * H1 + col];
        acc += xv.w * sW[(k0 + 3) * H1 + col];
      }
      y[(long long)row * H1 + col] = acc;
    }
  }
}

// ------ fused: agg1 = gather(y), h = relu((1+e1)y+agg1+c1), z = h @ M2 -----
// one wave (64 lanes) per node; 4 nodes per 256-thread block
__global__ __launch_bounds__(256) void gin2_fused(
    const float* __restrict__ y, const int* __restrict__ row_ptr,
    const int* __restrict__ csr_src, const float* __restrict__ M2,
    const float* __restrict__ c1, const float* __restrict__ eps1p,
    float* __restrict__ z) {
  __shared__ float sM2[H1 * H2];  // 8 KiB
  __shared__ float sc1[H1];
  __shared__ float sh[4][H1];
  int tid = threadIdx.x;
  for (int i = tid; i < H1 * H2; i += 256) sM2[i] = M2[i];
  if (tid < H1) sc1[tid] = c1[tid];
  __syncthreads();
  int wave = tid >> 6, lane = tid & 63;
  int node = blockIdx.x * 4 + wave;
  float eps1 = 1.0f + *eps1p;
  float h = 0.f;
  if (node < N_NODES) {
    int start = row_ptr[node], end = row_ptr[node + 1];
    float agg = 0.f;
    for (int e = start; e < end; ++e) {
      int s = csr_src[e];
      agg += y[(long long)s * H1 + lane];
    }
    h = fmaxf(eps1 * y[(long long)node * H1 + lane] + agg + sc1[lane], 0.f);
  }
  sh[wave][lane] = h;
  __syncthreads();
  if (node < N_NODES) {
    int o = lane & 31, half = lane >> 5;
    float acc = 0.f;
#pragma unroll
    for (int k = 0; k < 32; ++k) {
      int kk = half * 32 + k;
      acc += sh[wave][kk] * sM2[kk * H2 + o];
    }
    acc += __shfl_xor(acc, 32);
    if (half == 0) z[(long long)node * H2 + o] = acc;
  }
}

// -- fused: agg2 = gather(z), h2 = relu((1+e2)z+agg2+c2), p=h2.wl, r=h2.wr --
// 32 lanes per node; 8 nodes per 256-thread block
__global__ __launch_bounds__(256) void gin3_fused(
    const float* __restrict__ z, const int* __restrict__ row_ptr,
    const int* __restrict__ csr_src, const float* __restrict__ c2,
    const float* __restrict__ eps2p, const float* __restrict__ wl,
    const float* __restrict__ wr, float* __restrict__ p,
    float* __restrict__ r) {
  int idx = blockIdx.x * 256 + threadIdx.x;
  int node = idx >> 5;
  if (node >= N_NODES) return;
  int f = idx & 31;
  int start = row_ptr[node], end = row_ptr[node + 1];
  float agg = 0.f;
  for (int e = start; e < end; ++e) {
    int s = csr_src[e];
    agg += z[(long long)s * H2 + f];
  }
  float eps2 = 1.0f + *eps2p;
  float h = fmaxf(eps2 * z[(long long)node * H2 + f] + agg + c2[f], 0.f);
  float pd = h * wl[f];
  float rd = h * wr[f];
#pragma unroll
  for (int m = 16; m >= 1; m >>= 1) {
    pd += __shfl_xor(pd, m, 32);
    rd += __shfl_xor(rd, m, 32);
  }
  if (f == 0) {
    p[node] = pd;
    r[node] = rd;
  }
}

// ---- SAGE: mean of ew*p[src] over in-edges + root path, relu, write out ---
// 16 lanes per node; 16 nodes per 256-thread block
__global__ __launch_bounds__(256) void sage_out(
    const int* __restrict__ row_ptr, const int* __restrict__ csr_src,
    const float* __restrict__ csr_w, const float* __restrict__ p,
    const float* __restrict__ r, const float* __restrict__ blp,
    float* __restrict__ out) {
  int idx = blockIdx.x * 256 + threadIdx.x;
  int node = idx >> 4;
  if (node >= N_NODES) return;
  int l = idx & 15;
  int start = row_ptr[node], end = row_ptr[node + 1];
  float acc = 0.f;
  for (int e = start + l; e < end; e += 16) acc += csr_w[e] * p[csr_src[e]];
#pragma unroll
  for (int m = 8; m >= 1; m >>= 1) acc += __shfl_xor(acc, m, 16);
  if (l == 0) {
    float mean = acc / fmaxf((float)(end - start), 1.0f);
    out[node] = fmaxf(mean + blp[0] + r[node], 0.f);
  }
}

extern "C" void kernel_launch(void* const* d_in, const int* in_sizes, int n_in,
                              void* d_out, int out_size, void* d_ws,
                              size_t ws_size, hipStream_t stream) {
  const float* x = (const float*)d_in[0];
  const int* ei = (const int*)d_in[1];
  const float* ea = (const float*)d_in[2];
  const float* w1a = (const float*)d_in[3];
  const float* b1a = (const float*)d_in[4];
  const float* w1b = (const float*)d_in[5];
  const float* b1b = (const float*)d_in[6];
  const float* eps1 = (const float*)d_in[7];
  const float* w2a = (const float*)d_in[8];
  const float* b2a = (const float*)d_in[9];
  const float* w2b = (const float*)d_in[10];
  const float* b2b = (const float*)d_in[11];
  const float* eps2 = (const float*)d_in[12];
  const float* wl = (const float*)d_in[13];
  const float* bl = (const float*)d_in[14];
  const float* wr = (const float*)d_in[15];
  float* out = (float*)d_out;

  // workspace layout
  float* ws = (float*)d_ws;
  float* M1 = ws;                              // 8192
  float* c1 = M1 + F_IN * H1;                  // 64
  float* M2 = c1 + H1;                         // 2048
  float* c2 = M2 + H1 * H2;                    // 32
  float* y = c2 + H2;                          // N*64
  float* z = y + (long long)N_NODES * H1;      // N*32
  float* p = z + (long long)N_NODES * H2;      // N
  float* r = p + N_NODES;                      // N
  float* csr_w = r + N_NODES;                  // E
  int* counts = (int*)(csr_w + N_EDGES);       // N
  int* cursor = counts + N_NODES;              // N
  int* row_ptr = cursor + N_NODES;             // N+1
  int* csr_src = row_ptr + N_NODES + 1;        // E
  int* bsums = csr_src + N_EDGES;              // NBLK
  int* boffs = bsums + NBLK;                   // NBLK

  hipMemsetAsync(counts, 0, sizeof(int) * (size_t)N_NODES, stream);

  prep_weights<<<41, 256, 0, stream>>>(w1a, b1a, w1b, b1b, w2a, b2a, w2b, b2b,
                                       M1, c1, M2, c2);

  count_edges<<<(N_EDGES + 255) / 256, 256, 0, stream>>>(ei, counts);
  block_sums<<<NBLK, 256, 0, stream>>>(counts, bsums);
  scan_bsums<<<1, 256, 0, stream>>>(bsums, boffs, row_ptr);
  emit_rowptr<<<NBLK, 256, 0, stream>>>(counts, boffs, row_ptr, cursor);
  fill_csr<<<(N_EDGES + 255) / 256, 256, 0, stream>>>(ei, ea, cursor, csr_src,
                                                      csr_w);

  gemm1<<<(N_NODES + 31) / 32, 256, 0, stream>>>(x, M1, y);

  gin2_fused<<<(N_NODES + 3) / 4, 256, 0, stream>>>(y, row_ptr, csr_src, M2,
                                                    c1, eps1, z);

  gin3_fused<<<(N_NODES * 32 + 255) / 256, 256, 0, stream>>>(
      z, row_ptr, csr_src, c2, eps2, wl, wr, p, r);

  sage_out<<<(N_NODES * 16 + 255) / 256, 256, 0, stream>>>(row_ptr, csr_src,
                                                           csr_w, p, r, bl, out);
}

// Round 4
// 291.784 us; speedup vs baseline: 1.8416x; 1.1704x over previous
//
#include <hip/hip_runtime.h>

#define N_NODES 50000
#define N_EDGES 600000
#define F_IN 128
#define H1 64
#define H2 32
#define NBLK ((N_NODES + 255) / 256)  // 196 scan blocks

// ---------------------------------------------------------------------------
// Fold each GIN MLP (two linears, no inner activation) into one matrix+bias.
// ---------------------------------------------------------------------------
__global__ __launch_bounds__(256) void prep_weights(
    const float* __restrict__ w1a, const float* __restrict__ b1a,
    const float* __restrict__ w1b, const float* __restrict__ b1b,
    const float* __restrict__ w2a, const float* __restrict__ b2a,
    const float* __restrict__ w2b, const float* __restrict__ b2b,
    float* __restrict__ M1, float* __restrict__ c1,
    float* __restrict__ M2, float* __restrict__ c2) {
  int i = blockIdx.x * 256 + threadIdx.x;
  if (i < F_IN * H1) {
    int f = i >> 6, h = i & 63;
    float s = 0.f;
    for (int m = 0; m < H1; ++m) s += w1a[m * F_IN + f] * w1b[h * H1 + m];
    M1[i] = s;
    return;
  }
  i -= F_IN * H1;
  if (i < H1) {
    float s = b1b[i];
    for (int m = 0; m < H1; ++m) s += b1a[m] * w1b[i * H1 + m];
    c1[i] = s;
    return;
  }
  i -= H1;
  if (i < H1 * H2) {
    int h = i >> 5, o = i & 31;
    float s = 0.f;
    for (int m = 0; m < H2; ++m) s += w2a[m * H1 + h] * w2b[o * H2 + m];
    M2[i] = s;
    return;
  }
  i -= H1 * H2;
  if (i < H2) {
    float s = b2b[i];
    for (int m = 0; m < H2; ++m) s += b2a[m] * w2b[i * H2 + m];
    c2[i] = s;
  }
}

// -------------------- CSR build (by destination) ---------------------------
__global__ __launch_bounds__(256) void count_edges(const int* __restrict__ ei,
                                                   int* __restrict__ counts) {
  int e = blockIdx.x * 256 + threadIdx.x;
  if (e >= N_EDGES) return;
  atomicAdd(&counts[ei[N_EDGES + e]], 1);
}

__global__ __launch_bounds__(256) void block_sums(const int* __restrict__ counts,
                                                  int* __restrict__ bsums) {
  __shared__ int s[256];
  int t = threadIdx.x;
  int i = blockIdx.x * 256 + t;
  s[t] = (i < N_NODES) ? counts[i] : 0;
  __syncthreads();
  for (int off = 128; off > 0; off >>= 1) {
    if (t < off) s[t] += s[t + off];
    __syncthreads();
  }
  if (t == 0) bsums[blockIdx.x] = s[0];
}

__global__ __launch_bounds__(256) void scan_bsums(const int* __restrict__ bsums,
                                                  int* __restrict__ boffs,
                                                  int* __restrict__ row_ptr) {
  __shared__ int s[256];
  int t = threadIdx.x;
  int v = (t < NBLK) ? bsums[t] : 0;
  s[t] = v;
  __syncthreads();
  for (int off = 1; off < 256; off <<= 1) {
    int u = (t >= off) ? s[t - off] : 0;
    __syncthreads();
    s[t] += u;
    __syncthreads();
  }
  if (t < NBLK) boffs[t] = s[t] - v;
  if (t == 255) row_ptr[N_NODES] = s[255];
}

__global__ __launch_bounds__(256) void emit_rowptr(const int* __restrict__ counts,
                                                   const int* __restrict__ boffs,
                                                   int* __restrict__ row_ptr,
                                                   int* __restrict__ cursor) {
  __shared__ int s[256];
  int t = threadIdx.x;
  int i = blockIdx.x * 256 + t;
  int v = (i < N_NODES) ? counts[i] : 0;
  s[t] = v;
  __syncthreads();
  for (int off = 1; off < 256; off <<= 1) {
    int u = (t >= off) ? s[t - off] : 0;
    __syncthreads();
    s[t] += u;
    __syncthreads();
  }
  if (i < N_NODES) {
    int ex = boffs[blockIdx.x] + s[t] - v;
    row_ptr[i] = ex;
    cursor[i] = ex;
  }
}

__global__ __launch_bounds__(256) void fill_csr(const int* __restrict__ ei,
                                                const float* __restrict__ ea,
                                                int* __restrict__ cursor,
                                                int* __restrict__ csr_src,
                                                float* __restrict__ csr_w) {
  int e = blockIdx.x * 256 + threadIdx.x;
  if (e >= N_EDGES) return;
  int s = ei[e];
  int d = ei[N_EDGES + e];
  int pos = atomicAdd(&cursor[d], 1);
  csr_src[pos] = s;
  csr_w[pos] = ea[e];
}

// -------------------- y = x @ M1  (N x 128 -> N x 64) ----------------------
__global__ __launch_bounds__(256) void gemm1(const float* __restrict__ x,
                                             const float* __restrict__ M1,
                                             float* __restrict__ y) {
  __shared__ float sW[F_IN * H1];  // 32 KiB
  int tid = threadIdx.x;
  for (int i = tid; i < F_IN * H1; i += 256) sW[i] = M1[i];
  __syncthreads();
  int col = tid & 63;
  int rg = tid >> 6;  // 0..3
  int base = blockIdx.x * 32;
  for (int i = 0; i < 8; ++i) {
    int row = base + rg * 8 + i;
    if (row < N_NODES) {
      const float* xr = x + (long long)row * F_IN;
      float acc = 0.f;
#pragma unroll
      for (int k0 = 0; k0 < F_IN; k0 += 4) {
        float4 xv = *reinterpret_cast<const float4*>(xr + k0);
        acc += xv.x * sW[(k0 + 0) * H1 + col];
        acc += xv.y * sW[(k0 + 1) * H1 + col];
        acc += xv.z * sW[(k0 + 2) * H1 + col];
        acc += xv.w * sW[(k0 + 3) * H1 + col];
      }
      y[(long long)row * H1 + col] = acc;
    }
  }
}

// ------ fused: agg1 = gather(y), h = relu((1+e1)y+agg1+c1), z = h @ M2 -----
// one wave (64 lanes) per node; 4 nodes per 256-thread block.
// Gather unrolled x4: 4 independent outstanding loads per wave (MLP).
__global__ __launch_bounds__(256) void gin2_fused(
    const float* __restrict__ y, const int* __restrict__ row_ptr,
    const int* __restrict__ csr_src, const float* __restrict__ M2,
    const float* __restrict__ c1, const float* __restrict__ eps1p,
    float* __restrict__ z) {
  __shared__ float sM2[H1 * H2];  // 8 KiB
  __shared__ float sc1[H1];
  __shared__ float sh[4][H1];
  int tid = threadIdx.x;
  for (int i = tid; i < H1 * H2; i += 256) sM2[i] = M2[i];
  if (tid < H1) sc1[tid] = c1[tid];
  __syncthreads();
  int wave = tid >> 6, lane = tid & 63;
  int node = blockIdx.x * 4 + wave;
  float eps1 = 1.0f + *eps1p;
  float h = 0.f;
  if (node < N_NODES) {
    int start = row_ptr[node], end = row_ptr[node + 1];
    float agg = 0.f;
    int e = start;
    for (; e + 4 <= end; e += 4) {
      int s0 = csr_src[e + 0];
      int s1 = csr_src[e + 1];
      int s2 = csr_src[e + 2];
      int s3 = csr_src[e + 3];
      float a0 = y[(long long)s0 * H1 + lane];
      float a1 = y[(long long)s1 * H1 + lane];
      float a2 = y[(long long)s2 * H1 + lane];
      float a3 = y[(long long)s3 * H1 + lane];
      agg += (a0 + a1) + (a2 + a3);
    }
    float t0 = 0.f, t1 = 0.f, t2 = 0.f;
    if (e + 0 < end) t0 = y[(long long)csr_src[e + 0] * H1 + lane];
    if (e + 1 < end) t1 = y[(long long)csr_src[e + 1] * H1 + lane];
    if (e + 2 < end) t2 = y[(long long)csr_src[e + 2] * H1 + lane];
    agg += (t0 + t1) + t2;
    h = fmaxf(eps1 * y[(long long)node * H1 + lane] + agg + sc1[lane], 0.f);
  }
  sh[wave][lane] = h;
  __syncthreads();
  if (node < N_NODES) {
    int o = lane & 31, half = lane >> 5;
    float acc = 0.f;
#pragma unroll
    for (int k = 0; k < 32; ++k) {
      int kk = half * 32 + k;
      acc += sh[wave][kk] * sM2[kk * H2 + o];
    }
    acc += __shfl_xor(acc, 32);
    if (half == 0) z[(long long)node * H2 + o] = acc;
  }
}

// -- fused: agg2 = gather(z), h2 = relu((1+e2)z+agg2+c2), p=h2.wl, r=h2.wr --
// 32 lanes per node; 8 nodes per 256-thread block; gather unrolled x4.
__global__ __launch_bounds__(256) void gin3_fused(
    const float* __restrict__ z, const int* __restrict__ row_ptr,
    const int* __restrict__ csr_src, const float* __restrict__ c2,
    const float* __restrict__ eps2p, const float* __restrict__ wl,
    const float* __restrict__ wr, float* __restrict__ p,
    float* __restrict__ r) {
  int idx = blockIdx.x * 256 + threadIdx.x;
  int node = idx >> 5;
  if (node >= N_NODES) return;
  int f = idx & 31;
  int start = row_ptr[node], end = row_ptr[node + 1];
  float agg = 0.f;
  int e = start;
  for (; e + 4 <= end; e += 4) {
    int s0 = csr_src[e + 0];
    int s1 = csr_src[e + 1];
    int s2 = csr_src[e + 2];
    int s3 = csr_src[e + 3];
    float a0 = z[(long long)s0 * H2 + f];
    float a1 = z[(long long)s1 * H2 + f];
    float a2 = z[(long long)s2 * H2 + f];
    float a3 = z[(long long)s3 * H2 + f];
    agg += (a0 + a1) + (a2 + a3);
  }
  float t0 = 0.f, t1 = 0.f, t2 = 0.f;
  if (e + 0 < end) t0 = z[(long long)csr_src[e + 0] * H2 + f];
  if (e + 1 < end) t1 = z[(long long)csr_src[e + 1] * H2 + f];
  if (e + 2 < end) t2 = z[(long long)csr_src[e + 2] * H2 + f];
  agg += (t0 + t1) + t2;
  float eps2 = 1.0f + *eps2p;
  float h = fmaxf(eps2 * z[(long long)node * H2 + f] + agg + c2[f], 0.f);
  float pd = h * wl[f];
  float rd = h * wr[f];
#pragma unroll
  for (int m = 16; m >= 1; m >>= 1) {
    pd += __shfl_xor(pd, m, 32);
    rd += __shfl_xor(rd, m, 32);
  }
  if (f == 0) {
    p[node] = pd;
    r[node] = rd;
  }
}

// ---- SAGE: mean of ew*p[src] over in-edges + root path, relu, write out ---
__global__ __launch_bounds__(256) void sage_out(
    const int* __restrict__ row_ptr, const int* __restrict__ csr_src,
    const float* __restrict__ csr_w, const float* __restrict__ p,
    const float* __restrict__ r, const float* __restrict__ blp,
    float* __restrict__ out) {
  int idx = blockIdx.x * 256 + threadIdx.x;
  int node = idx >> 4;
  if (node >= N_NODES) return;
  int l = idx & 15;
  int start = row_ptr[node], end = row_ptr[node + 1];
  float acc = 0.f;
  for (int e = start + l; e < end; e += 16) acc += csr_w[e] * p[csr_src[e]];
#pragma unroll
  for (int m = 8; m >= 1; m >>= 1) acc += __shfl_xor(acc, m, 16);
  if (l == 0) {
    float mean = acc / fmaxf((float)(end - start), 1.0f);
    out[node] = fmaxf(mean + blp[0] + r[node], 0.f);
  }
}

extern "C" void kernel_launch(void* const* d_in, const int* in_sizes, int n_in,
                              void* d_out, int out_size, void* d_ws,
                              size_t ws_size, hipStream_t stream) {
  const float* x = (const float*)d_in[0];
  const int* ei = (const int*)d_in[1];
  const float* ea = (const float*)d_in[2];
  const float* w1a = (const float*)d_in[3];
  const float* b1a = (const float*)d_in[4];
  const float* w1b = (const float*)d_in[5];
  const float* b1b = (const float*)d_in[6];
  const float* eps1 = (const float*)d_in[7];
  const float* w2a = (const float*)d_in[8];
  const float* b2a = (const float*)d_in[9];
  const float* w2b = (const float*)d_in[10];
  const float* b2b = (const float*)d_in[11];
  const float* eps2 = (const float*)d_in[12];
  const float* wl = (const float*)d_in[13];
  const float* bl = (const float*)d_in[14];
  const float* wr = (const float*)d_in[15];
  float* out = (float*)d_out;

  // workspace layout
  float* ws = (float*)d_ws;
  float* M1 = ws;                              // 8192
  float* c1 = M1 + F_IN * H1;                  // 64
  float* M2 = c1 + H1;                         // 2048
  float* c2 = M2 + H1 * H2;                    // 32
  float* y = c2 + H2;                          // N*64
  float* z = y + (long long)N_NODES * H1;      // N*32
  float* p = z + (long long)N_NODES * H2;      // N
  float* r = p + N_NODES;                      // N
  float* csr_w = r + N_NODES;                  // E
  int* counts = (int*)(csr_w + N_EDGES);       // N
  int* cursor = counts + N_NODES;              // N
  int* row_ptr = cursor + N_NODES;             // N+1
  int* csr_src = row_ptr + N_NODES + 1;        // E
  int* bsums = csr_src + N_EDGES;              // NBLK
  int* boffs = bsums + NBLK;                   // NBLK

  hipMemsetAsync(counts, 0, sizeof(int) * (size_t)N_NODES, stream);

  prep_weights<<<41, 256, 0, stream>>>(w1a, b1a, w1b, b1b, w2a, b2a, w2b, b2b,
                                       M1, c1, M2, c2);

  count_edges<<<(N_EDGES + 255) / 256, 256, 0, stream>>>(ei, counts);
  block_sums<<<NBLK, 256, 0, stream>>>(counts, bsums);
  scan_bsums<<<1, 256, 0, stream>>>(bsums, boffs, row_ptr);
  emit_rowptr<<<NBLK, 256, 0, stream>>>(counts, boffs, row_ptr, cursor);
  fill_csr<<<(N_EDGES + 255) / 256, 256, 0, stream>>>(ei, ea, cursor, csr_src,
                                                      csr_w);

  gemm1<<<(N_NODES + 31) / 32, 256, 0, stream>>>(x, M1, y);

  gin2_fused<<<(N_NODES + 3) / 4, 256, 0, stream>>>(y, row_ptr, csr_src, M2,
                                                    c1, eps1, z);

  gin3_fused<<<(N_NODES * 32 + 255) / 256, 256, 0, stream>>>(
      z, row_ptr, csr_src, c2, eps2, wl, wr, p, r);

  sage_out<<<(N_NODES * 16 + 255) / 256, 256, 0, stream>>>(row_ptr, csr_src,
                                                           csr_w, p, r, bl, out);
}

// Round 5
// 250.261 us; speedup vs baseline: 2.1471x; 1.1659x over previous
//
#include <hip/hip_runtime.h>

#define N_NODES 50000
#define N_EDGES 600000
#define F_IN 128
#define H1 64
#define H2 32
#define NBLK ((N_NODES + 255) / 256)  // 196 scan blocks

// ---------------------------------------------------------------------------
// Fold each GIN MLP (two linears, no inner activation) into one matrix+bias.
// ---------------------------------------------------------------------------
__global__ __launch_bounds__(256) void prep_weights(
    const float* __restrict__ w1a, const float* __restrict__ b1a,
    const float* __restrict__ w1b, const float* __restrict__ b1b,
    const float* __restrict__ w2a, const float* __restrict__ b2a,
    const float* __restrict__ w2b, const float* __restrict__ b2b,
    float* __restrict__ M1, float* __restrict__ c1,
    float* __restrict__ M2, float* __restrict__ c2) {
  int i = blockIdx.x * 256 + threadIdx.x;
  if (i < F_IN * H1) {
    int f = i >> 6, h = i & 63;
    float s = 0.f;
    for (int m = 0; m < H1; ++m) s += w1a[m * F_IN + f] * w1b[h * H1 + m];
    M1[i] = s;
    return;
  }
  i -= F_IN * H1;
  if (i < H1) {
    float s = b1b[i];
    for (int m = 0; m < H1; ++m) s += b1a[m] * w1b[i * H1 + m];
    c1[i] = s;
    return;
  }
  i -= H1;
  if (i < H1 * H2) {
    int h = i >> 5, o = i & 31;
    float s = 0.f;
    for (int m = 0; m < H2; ++m) s += w2a[m * H1 + h] * w2b[o * H2 + m];
    M2[i] = s;
    return;
  }
  i -= H1 * H2;
  if (i < H2) {
    float s = b2b[i];
    for (int m = 0; m < H2; ++m) s += b2a[m] * w2b[i * H2 + m];
    c2[i] = s;
  }
}

// -------------------- CSR build (by destination) ---------------------------
__global__ __launch_bounds__(256) void count_edges(const int* __restrict__ ei,
                                                   int* __restrict__ counts) {
  int e = blockIdx.x * 256 + threadIdx.x;
  if (e >= N_EDGES) return;
  atomicAdd(&counts[ei[N_EDGES + e]], 1);
}

__global__ __launch_bounds__(256) void block_sums(const int* __restrict__ counts,
                                                  int* __restrict__ bsums) {
  __shared__ int s[256];
  int t = threadIdx.x;
  int i = blockIdx.x * 256 + t;
  s[t] = (i < N_NODES) ? counts[i] : 0;
  __syncthreads();
  for (int off = 128; off > 0; off >>= 1) {
    if (t < off) s[t] += s[t + off];
    __syncthreads();
  }
  if (t == 0) bsums[blockIdx.x] = s[0];
}

__global__ __launch_bounds__(256) void scan_bsums(const int* __restrict__ bsums,
                                                  int* __restrict__ boffs,
                                                  int* __restrict__ row_ptr) {
  __shared__ int s[256];
  int t = threadIdx.x;
  int v = (t < NBLK) ? bsums[t] : 0;
  s[t] = v;
  __syncthreads();
  for (int off = 1; off < 256; off <<= 1) {
    int u = (t >= off) ? s[t - off] : 0;
    __syncthreads();
    s[t] += u;
    __syncthreads();
  }
  if (t < NBLK) boffs[t] = s[t] - v;
  if (t == 255) row_ptr[N_NODES] = s[255];
}

__global__ __launch_bounds__(256) void emit_rowptr(const int* __restrict__ counts,
                                                   const int* __restrict__ boffs,
                                                   int* __restrict__ row_ptr,
                                                   int* __restrict__ cursor) {
  __shared__ int s[256];
  int t = threadIdx.x;
  int i = blockIdx.x * 256 + t;
  int v = (i < N_NODES) ? counts[i] : 0;
  s[t] = v;
  __syncthreads();
  for (int off = 1; off < 256; off <<= 1) {
    int u = (t >= off) ? s[t - off] : 0;
    __syncthreads();
    s[t] += u;
    __syncthreads();
  }
  if (i < N_NODES) {
    int ex = boffs[blockIdx.x] + s[t] - v;
    row_ptr[i] = ex;
    cursor[i] = ex;
  }
}

__global__ __launch_bounds__(256) void fill_csr(const int* __restrict__ ei,
                                                const float* __restrict__ ea,
                                                int* __restrict__ cursor,
                                                int* __restrict__ csr_src,
                                                float* __restrict__ csr_w) {
  int e = blockIdx.x * 256 + threadIdx.x;
  if (e >= N_EDGES) return;
  int s = ei[e];
  int d = ei[N_EDGES + e];
  int pos = atomicAdd(&cursor[d], 1);
  csr_src[pos] = s;
  csr_w[pos] = ea[e];
}

// -------------------- y = x @ M1  (N x 128 -> N x 64) ----------------------
// Register-tiled: block = 64 rows x 64 cols, 16x16 threads, 4x4 acc/thread.
// Per k-step: 2x ds_read_b128 feed 16 FMAs (LDS:FMA = 1:8).
__global__ __launch_bounds__(256) void gemm1(const float* __restrict__ x,
                                             const float* __restrict__ M1,
                                             float* __restrict__ y) {
  __shared__ float sW[F_IN * H1];   // 32 KiB, [k][col]
  __shared__ float sX[32][H1];      // 8 KiB,  [k][row] (transposed chunk)
  int tid = threadIdx.x;
  for (int i = tid; i < F_IN * H1; i += 256) sW[i] = M1[i];

  int row0 = blockIdx.x * 64;
  int tr = tid >> 4;   // 0..15 (row tile)
  int tc = tid & 15;   // 0..15 (col tile)
  int lrow = tid & 63; // staging row
  int kgrp = tid >> 6; // 0..3, 8 k's each
  const float* xrow = x + (long long)(row0 + lrow) * F_IN;
  bool rvalid = (row0 + lrow) < N_NODES;

  float acc[4][4] = {{0.f}};

  for (int kc = 0; kc < 4; ++kc) {
    float4 v0 = make_float4(0.f, 0.f, 0.f, 0.f);
    float4 v1 = make_float4(0.f, 0.f, 0.f, 0.f);
    if (rvalid) {
      v0 = *reinterpret_cast<const float4*>(xrow + kc * 32 + kgrp * 8);
      v1 = *reinterpret_cast<const float4*>(xrow + kc * 32 + kgrp * 8 + 4);
    }
    __syncthreads();  // previous chunk fully consumed (also covers sW fill)
    sX[kgrp * 8 + 0][lrow] = v0.x;
    sX[kgrp * 8 + 1][lrow] = v0.y;
    sX[kgrp * 8 + 2][lrow] = v0.z;
    sX[kgrp * 8 + 3][lrow] = v0.w;
    sX[kgrp * 8 + 4][lrow] = v1.x;
    sX[kgrp * 8 + 5][lrow] = v1.y;
    sX[kgrp * 8 + 6][lrow] = v1.z;
    sX[kgrp * 8 + 7][lrow] = v1.w;
    __syncthreads();
#pragma unroll
    for (int k = 0; k < 32; ++k) {
      float4 a = *reinterpret_cast<const float4*>(&sX[k][tr * 4]);
      float4 b = *reinterpret_cast<const float4*>(&sW[(kc * 32 + k) * H1 + tc * 4]);
      acc[0][0] += a.x * b.x; acc[0][1] += a.x * b.y;
      acc[0][2] += a.x * b.z; acc[0][3] += a.x * b.w;
      acc[1][0] += a.y * b.x; acc[1][1] += a.y * b.y;
      acc[1][2] += a.y * b.z; acc[1][3] += a.y * b.w;
      acc[2][0] += a.z * b.x; acc[2][1] += a.z * b.y;
      acc[2][2] += a.z * b.z; acc[2][3] += a.z * b.w;
      acc[3][0] += a.w * b.x; acc[3][1] += a.w * b.y;
      acc[3][2] += a.w * b.z; acc[3][3] += a.w * b.w;
    }
  }
#pragma unroll
  for (int i = 0; i < 4; ++i) {
    int row = row0 + tr * 4 + i;
    if (row < N_NODES) {
      float4 o = make_float4(acc[i][0], acc[i][1], acc[i][2], acc[i][3]);
      *reinterpret_cast<float4*>(&y[(long long)row * H1 + tc * 4]) = o;
    }
  }
}

// ------ fused: agg1 = gather(y), h = relu((1+e1)y+agg1+c1), z = h @ M2 -----
// one wave (64 lanes) per node; 4 nodes per 256-thread block.
// Gather unrolled x4: 4 independent outstanding loads per wave (MLP).
__global__ __launch_bounds__(256) void gin2_fused(
    const float* __restrict__ y, const int* __restrict__ row_ptr,
    const int* __restrict__ csr_src, const float* __restrict__ M2,
    const float* __restrict__ c1, const float* __restrict__ eps1p,
    float* __restrict__ z) {
  __shared__ float sM2[H1 * H2];  // 8 KiB
  __shared__ float sc1[H1];
  __shared__ float sh[4][H1];
  int tid = threadIdx.x;
  for (int i = tid; i < H1 * H2; i += 256) sM2[i] = M2[i];
  if (tid < H1) sc1[tid] = c1[tid];
  __syncthreads();
  int wave = tid >> 6, lane = tid & 63;
  int node = blockIdx.x * 4 + wave;
  float eps1 = 1.0f + *eps1p;
  float h = 0.f;
  if (node < N_NODES) {
    int start = row_ptr[node], end = row_ptr[node + 1];
    float agg = 0.f;
    int e = start;
    for (; e + 4 <= end; e += 4) {
      int s0 = csr_src[e + 0];
      int s1 = csr_src[e + 1];
      int s2 = csr_src[e + 2];
      int s3 = csr_src[e + 3];
      float a0 = y[(long long)s0 * H1 + lane];
      float a1 = y[(long long)s1 * H1 + lane];
      float a2 = y[(long long)s2 * H1 + lane];
      float a3 = y[(long long)s3 * H1 + lane];
      agg += (a0 + a1) + (a2 + a3);
    }
    float t0 = 0.f, t1 = 0.f, t2 = 0.f;
    if (e + 0 < end) t0 = y[(long long)csr_src[e + 0] * H1 + lane];
    if (e + 1 < end) t1 = y[(long long)csr_src[e + 1] * H1 + lane];
    if (e + 2 < end) t2 = y[(long long)csr_src[e + 2] * H1 + lane];
    agg += (t0 + t1) + t2;
    h = fmaxf(eps1 * y[(long long)node * H1 + lane] + agg + sc1[lane], 0.f);
  }
  sh[wave][lane] = h;
  __syncthreads();
  if (node < N_NODES) {
    int o = lane & 31, half = lane >> 5;
    float acc = 0.f;
#pragma unroll
    for (int k = 0; k < 32; ++k) {
      int kk = half * 32 + k;
      acc += sh[wave][kk] * sM2[kk * H2 + o];
    }
    acc += __shfl_xor(acc, 32);
    if (half == 0) z[(long long)node * H2 + o] = acc;
  }
}

// -- fused: agg2 = gather(z), h2 = relu((1+e2)z+agg2+c2), p=h2.wl, r=h2.wr --
// 32 lanes per node; 8 nodes per 256-thread block; gather unrolled x4.
__global__ __launch_bounds__(256) void gin3_fused(
    const float* __restrict__ z, const int* __restrict__ row_ptr,
    const int* __restrict__ csr_src, const float* __restrict__ c2,
    const float* __restrict__ eps2p, const float* __restrict__ wl,
    const float* __restrict__ wr, float* __restrict__ p,
    float* __restrict__ r) {
  int idx = blockIdx.x * 256 + threadIdx.x;
  int node = idx >> 5;
  if (node >= N_NODES) return;
  int f = idx & 31;
  int start = row_ptr[node], end = row_ptr[node + 1];
  float agg = 0.f;
  int e = start;
  for (; e + 4 <= end; e += 4) {
    int s0 = csr_src[e + 0];
    int s1 = csr_src[e + 1];
    int s2 = csr_src[e + 2];
    int s3 = csr_src[e + 3];
    float a0 = z[(long long)s0 * H2 + f];
    float a1 = z[(long long)s1 * H2 + f];
    float a2 = z[(long long)s2 * H2 + f];
    float a3 = z[(long long)s3 * H2 + f];
    agg += (a0 + a1) + (a2 + a3);
  }
  float t0 = 0.f, t1 = 0.f, t2 = 0.f;
  if (e + 0 < end) t0 = z[(long long)csr_src[e + 0] * H2 + f];
  if (e + 1 < end) t1 = z[(long long)csr_src[e + 1] * H2 + f];
  if (e + 2 < end) t2 = z[(long long)csr_src[e + 2] * H2 + f];
  agg += (t0 + t1) + t2;
  float eps2 = 1.0f + *eps2p;
  float h = fmaxf(eps2 * z[(long long)node * H2 + f] + agg + c2[f], 0.f);
  float pd = h * wl[f];
  float rd = h * wr[f];
#pragma unroll
  for (int m = 16; m >= 1; m >>= 1) {
    pd += __shfl_xor(pd, m, 32);
    rd += __shfl_xor(rd, m, 32);
  }
  if (f == 0) {
    p[node] = pd;
    r[node] = rd;
  }
}

// ---- SAGE: mean of ew*p[src] over in-edges + root path, relu, write out ---
__global__ __launch_bounds__(256) void sage_out(
    const int* __restrict__ row_ptr, const int* __restrict__ csr_src,
    const float* __restrict__ csr_w, const float* __restrict__ p,
    const float* __restrict__ r, const float* __restrict__ blp,
    float* __restrict__ out) {
  int idx = blockIdx.x * 256 + threadIdx.x;
  int node = idx >> 4;
  if (node >= N_NODES) return;
  int l = idx & 15;
  int start = row_ptr[node], end = row_ptr[node + 1];
  float acc = 0.f;
  for (int e = start + l; e < end; e += 16) acc += csr_w[e] * p[csr_src[e]];
#pragma unroll
  for (int m = 8; m >= 1; m >>= 1) acc += __shfl_xor(acc, m, 16);
  if (l == 0) {
    float mean = acc / fmaxf((float)(end - start), 1.0f);
    out[node] = fmaxf(mean + blp[0] + r[node], 0.f);
  }
}

extern "C" void kernel_launch(void* const* d_in, const int* in_sizes, int n_in,
                              void* d_out, int out_size, void* d_ws,
                              size_t ws_size, hipStream_t stream) {
  const float* x = (const float*)d_in[0];
  const int* ei = (const int*)d_in[1];
  const float* ea = (const float*)d_in[2];
  const float* w1a = (const float*)d_in[3];
  const float* b1a = (const float*)d_in[4];
  const float* w1b = (const float*)d_in[5];
  const float* b1b = (const float*)d_in[6];
  const float* eps1 = (const float*)d_in[7];
  const float* w2a = (const float*)d_in[8];
  const float* b2a = (const float*)d_in[9];
  const float* w2b = (const float*)d_in[10];
  const float* b2b = (const float*)d_in[11];
  const float* eps2 = (const float*)d_in[12];
  const float* wl = (const float*)d_in[13];
  const float* bl = (const float*)d_in[14];
  const float* wr = (const float*)d_in[15];
  float* out = (float*)d_out;

  // workspace layout
  float* ws = (float*)d_ws;
  float* M1 = ws;                              // 8192
  float* c1 = M1 + F_IN * H1;                  // 64
  float* M2 = c1 + H1;                         // 2048
  float* c2 = M2 + H1 * H2;                    // 32
  float* y = c2 + H2;                          // N*64
  float* z = y + (long long)N_NODES * H1;      // N*32
  float* p = z + (long long)N_NODES * H2;      // N
  float* r = p + N_NODES;                      // N
  float* csr_w = r + N_NODES;                  // E
  int* counts = (int*)(csr_w + N_EDGES);       // N
  int* cursor = counts + N_NODES;              // N
  int* row_ptr = cursor + N_NODES;             // N+1
  int* csr_src = row_ptr + N_NODES + 1;        // E
  int* bsums = csr_src + N_EDGES;              // NBLK
  int* boffs = bsums + NBLK;                   // NBLK

  hipMemsetAsync(counts, 0, sizeof(int) * (size_t)N_NODES, stream);

  prep_weights<<<41, 256, 0, stream>>>(w1a, b1a, w1b, b1b, w2a, b2a, w2b, b2b,
                                       M1, c1, M2, c2);

  count_edges<<<(N_EDGES + 255) / 256, 256, 0, stream>>>(ei, counts);
  block_sums<<<NBLK, 256, 0, stream>>>(counts, bsums);
  scan_bsums<<<1, 256, 0, stream>>>(bsums, boffs, row_ptr);
  emit_rowptr<<<NBLK, 256, 0, stream>>>(counts, boffs, row_ptr, cursor);
  fill_csr<<<(N_EDGES + 255) / 256, 256, 0, stream>>>(ei, ea, cursor, csr_src,
                                                      csr_w);

  gemm1<<<(N_NODES + 63) / 64, 256, 0, stream>>>(x, M1, y);

  gin2_fused<<<(N_NODES + 3) / 4, 256, 0, stream>>>(y, row_ptr, csr_src, M2,
                                                    c1, eps1, z);

  gin3_fused<<<(N_NODES * 32 + 255) / 256, 256, 0, stream>>>(
      z, row_ptr, csr_src, c2, eps2, wl, wr, p, r);

  sage_out<<<(N_NODES * 16 + 255) / 256, 256, 0, stream>>>(row_ptr, csr_src,
                                                           csr_w, p, r, bl, out);
}

// Round 6
// 240.076 us; speedup vs baseline: 2.2382x; 1.0424x over previous
//
#include <hip/hip_runtime.h>

#define N_NODES 50000
#define N_EDGES 600000
#define F_IN 128
#define H1 64
#define H2 32
#define NBLK ((N_NODES + 255) / 256)   // 196 scan blocks
#define PREP_BLOCKS 41                 // 10336 weight elems / 256
#define CNT_BLOCKS ((N_EDGES / 4 + 255) / 256)  // 586

// ---- bf16 pack/unpack helpers (round-to-nearest-even) ---------------------
__device__ inline unsigned bf_round(float x) {
  unsigned u = __float_as_uint(x);
  u += 0x7FFFu + ((u >> 16) & 1u);
  return u >> 16;
}
__device__ inline unsigned pack_bf2(float a, float b) {
  return (bf_round(b) << 16) | bf_round(a);
}
__device__ inline float2 unpack_bf2(unsigned u) {
  return make_float2(__uint_as_float(u << 16), __uint_as_float(u & 0xFFFF0000u));
}

// ---------------------------------------------------------------------------
// Kernel A: fold GIN MLP weights (blocks 0..40)  +  count edges (rest).
//   M1[f][h] = sum_m w1a[m][f] * w1b[h][m]; c1 = w1b@b1a + b1b
//   M2[h][o] = sum_m w2a[m][h] * w2b[o][m]; c2 = w2b@b2a + b2b
// ---------------------------------------------------------------------------
__global__ __launch_bounds__(256) void prep_and_count(
    const float* __restrict__ w1a, const float* __restrict__ b1a,
    const float* __restrict__ w1b, const float* __restrict__ b1b,
    const float* __restrict__ w2a, const float* __restrict__ b2a,
    const float* __restrict__ w2b, const float* __restrict__ b2b,
    float* __restrict__ M1, float* __restrict__ c1,
    float* __restrict__ M2, float* __restrict__ c2,
    const int* __restrict__ ei, int* __restrict__ counts) {
  if (blockIdx.x >= PREP_BLOCKS) {
    int t = (blockIdx.x - PREP_BLOCKS) * 256 + threadIdx.x;
    if (t < N_EDGES / 4) {
      int4 d4 = *reinterpret_cast<const int4*>(&ei[N_EDGES + t * 4]);
      atomicAdd(&counts[d4.x], 1);
      atomicAdd(&counts[d4.y], 1);
      atomicAdd(&counts[d4.z], 1);
      atomicAdd(&counts[d4.w], 1);
    }
    return;
  }
  int i = blockIdx.x * 256 + threadIdx.x;
  if (i < F_IN * H1) {
    int f = i >> 6, h = i & 63;
    float s = 0.f;
    for (int m = 0; m < H1; ++m) s += w1a[m * F_IN + f] * w1b[h * H1 + m];
    M1[i] = s;
    return;
  }
  i -= F_IN * H1;
  if (i < H1) {
    float s = b1b[i];
    for (int m = 0; m < H1; ++m) s += b1a[m] * w1b[i * H1 + m];
    c1[i] = s;
    return;
  }
  i -= H1;
  if (i < H1 * H2) {
    int h = i >> 5, o = i & 31;
    float s = 0.f;
    for (int m = 0; m < H2; ++m) s += w2a[m * H1 + h] * w2b[o * H2 + m];
    M2[i] = s;
    return;
  }
  i -= H1 * H2;
  if (i < H2) {
    float s = b2b[i];
    for (int m = 0; m < H2; ++m) s += b2a[m] * w2b[i * H2 + m];
    c2[i] = s;
  }
}

// -------------------- CSR scan phases --------------------------------------
__global__ __launch_bounds__(256) void block_sums(const int* __restrict__ counts,
                                                  int* __restrict__ bsums) {
  __shared__ int s[256];
  int t = threadIdx.x;
  int i = blockIdx.x * 256 + t;
  s[t] = (i < N_NODES) ? counts[i] : 0;
  __syncthreads();
  for (int off = 128; off > 0; off >>= 1) {
    if (t < off) s[t] += s[t + off];
    __syncthreads();
  }
  if (t == 0) bsums[blockIdx.x] = s[0];
}

__global__ __launch_bounds__(256) void scan_bsums(const int* __restrict__ bsums,
                                                  int* __restrict__ boffs,
                                                  int* __restrict__ row_ptr) {
  __shared__ int s[256];
  int t = threadIdx.x;
  int v = (t < NBLK) ? bsums[t] : 0;
  s[t] = v;
  __syncthreads();
  for (int off = 1; off < 256; off <<= 1) {
    int u = (t >= off) ? s[t - off] : 0;
    __syncthreads();
    s[t] += u;
    __syncthreads();
  }
  if (t < NBLK) boffs[t] = s[t] - v;
  if (t == 255) row_ptr[N_NODES] = s[255];
}

__global__ __launch_bounds__(256) void emit_rowptr(const int* __restrict__ counts,
                                                   const int* __restrict__ boffs,
                                                   int* __restrict__ row_ptr,
                                                   int* __restrict__ cursor) {
  __shared__ int s[256];
  int t = threadIdx.x;
  int i = blockIdx.x * 256 + t;
  int v = (i < N_NODES) ? counts[i] : 0;
  s[t] = v;
  __syncthreads();
  for (int off = 1; off < 256; off <<= 1) {
    int u = (t >= off) ? s[t - off] : 0;
    __syncthreads();
    s[t] += u;
    __syncthreads();
  }
  if (i < N_NODES) {
    int ex = boffs[blockIdx.x] + s[t] - v;
    row_ptr[i] = ex;
    cursor[i] = ex;
  }
}

// fill packed CSR: one 8B scattered store per edge
__global__ __launch_bounds__(256) void fill_csr(const int* __restrict__ ei,
                                                const float* __restrict__ ea,
                                                int* __restrict__ cursor,
                                                int2* __restrict__ csr) {
  int e = blockIdx.x * 256 + threadIdx.x;
  if (e >= N_EDGES) return;
  int s = ei[e];
  int d = ei[N_EDGES + e];
  int pos = atomicAdd(&cursor[d], 1);
  csr[pos] = make_int2(s, __float_as_int(ea[e]));
}

// -------------------- y = x @ M1 -> packed bf16  (N x 128 -> N x 64) -------
// Register-tiled 64x64, 4x4 acc/thread, 2x ds_read_b128 per 16 FMAs.
__global__ __launch_bounds__(256) void gemm1(const float* __restrict__ x,
                                             const float* __restrict__ M1,
                                             unsigned* __restrict__ ybf) {
  __shared__ float sW[F_IN * H1];   // 32 KiB, [k][col]
  __shared__ float sX[32][H1];      // 8 KiB,  [k][row]
  int tid = threadIdx.x;
  for (int i = tid; i < F_IN * H1; i += 256) sW[i] = M1[i];

  int row0 = blockIdx.x * 64;
  int tr = tid >> 4;   // 0..15
  int tc = tid & 15;   // 0..15
  int lrow = tid & 63;
  int kgrp = tid >> 6; // 0..3
  const float* xrow = x + (long long)(row0 + lrow) * F_IN;
  bool rvalid = (row0 + lrow) < N_NODES;

  float acc[4][4] = {{0.f}};

  for (int kc = 0; kc < 4; ++kc) {
    float4 v0 = make_float4(0.f, 0.f, 0.f, 0.f);
    float4 v1 = make_float4(0.f, 0.f, 0.f, 0.f);
    if (rvalid) {
      v0 = *reinterpret_cast<const float4*>(xrow + kc * 32 + kgrp * 8);
      v1 = *reinterpret_cast<const float4*>(xrow + kc * 32 + kgrp * 8 + 4);
    }
    __syncthreads();
    sX[kgrp * 8 + 0][lrow] = v0.x;
    sX[kgrp * 8 + 1][lrow] = v0.y;
    sX[kgrp * 8 + 2][lrow] = v0.z;
    sX[kgrp * 8 + 3][lrow] = v0.w;
    sX[kgrp * 8 + 4][lrow] = v1.x;
    sX[kgrp * 8 + 5][lrow] = v1.y;
    sX[kgrp * 8 + 6][lrow] = v1.z;
    sX[kgrp * 8 + 7][lrow] = v1.w;
    __syncthreads();
#pragma unroll
    for (int k = 0; k < 32; ++k) {
      float4 a = *reinterpret_cast<const float4*>(&sX[k][tr * 4]);
      float4 b = *reinterpret_cast<const float4*>(&sW[(kc * 32 + k) * H1 + tc * 4]);
      acc[0][0] += a.x * b.x; acc[0][1] += a.x * b.y;
      acc[0][2] += a.x * b.z; acc[0][3] += a.x * b.w;
      acc[1][0] += a.y * b.x; acc[1][1] += a.y * b.y;
      acc[1][2] += a.y * b.z; acc[1][3] += a.y * b.w;
      acc[2][0] += a.z * b.x; acc[2][1] += a.z * b.y;
      acc[2][2] += a.z * b.z; acc[2][3] += a.z * b.w;
      acc[3][0] += a.w * b.x; acc[3][1] += a.w * b.y;
      acc[3][2] += a.w * b.z; acc[3][3] += a.w * b.w;
    }
  }
#pragma unroll
  for (int i = 0; i < 4; ++i) {
    int row = row0 + tr * 4 + i;
    if (row < N_NODES) {
      uint2 o;
      o.x = pack_bf2(acc[i][0], acc[i][1]);
      o.y = pack_bf2(acc[i][2], acc[i][3]);
      *reinterpret_cast<uint2*>(&ybf[(long long)row * 32 + tc * 2]) = o;
    }
  }
}

// ---- agg_h: h = relu((1+e1)*y_self + sum y_nb + c1), fp32 out -------------
// 32 lanes per node (lane j = features 2j,2j+1); 8 nodes / 256-thr block.
__global__ __launch_bounds__(256) void agg_h(
    const unsigned* __restrict__ ybf, const int* __restrict__ row_ptr,
    const int2* __restrict__ csr, const float* __restrict__ c1,
    const float* __restrict__ eps1p, float* __restrict__ h) {
  int tid = threadIdx.x;
  int node = blockIdx.x * 8 + (tid >> 5);
  if (node >= N_NODES) return;
  int j = tid & 31;
  int start = row_ptr[node], end = row_ptr[node + 1];
  float a0 = 0.f, a1 = 0.f;
  int e = start;
  for (; e + 4 <= end; e += 4) {
    int s0 = csr[e + 0].x;
    int s1 = csr[e + 1].x;
    int s2 = csr[e + 2].x;
    int s3 = csr[e + 3].x;
    float2 u0 = unpack_bf2(ybf[(unsigned)s0 * 32 + j]);
    float2 u1 = unpack_bf2(ybf[(unsigned)s1 * 32 + j]);
    float2 u2 = unpack_bf2(ybf[(unsigned)s2 * 32 + j]);
    float2 u3 = unpack_bf2(ybf[(unsigned)s3 * 32 + j]);
    a0 += (u0.x + u1.x) + (u2.x + u3.x);
    a1 += (u0.y + u1.y) + (u2.y + u3.y);
  }
  float2 t0 = make_float2(0.f, 0.f), t1 = make_float2(0.f, 0.f),
         t2 = make_float2(0.f, 0.f);
  if (e + 0 < end) t0 = unpack_bf2(ybf[(unsigned)csr[e + 0].x * 32 + j]);
  if (e + 1 < end) t1 = unpack_bf2(ybf[(unsigned)csr[e + 1].x * 32 + j]);
  if (e + 2 < end) t2 = unpack_bf2(ybf[(unsigned)csr[e + 2].x * 32 + j]);
  a0 += (t0.x + t1.x) + t2.x;
  a1 += (t0.y + t1.y) + t2.y;
  float eps1 = 1.0f + *eps1p;
  float2 self = unpack_bf2(ybf[(unsigned)node * 32 + j]);
  float2 c = *reinterpret_cast<const float2*>(&c1[2 * j]);
  float2 hv;
  hv.x = fmaxf(eps1 * self.x + a0 + c.x, 0.f);
  hv.y = fmaxf(eps1 * self.y + a1 + c.y, 0.f);
  *reinterpret_cast<float2*>(&h[(long long)node * H1 + 2 * j]) = hv;
}

// -------------------- z = h @ M2 -> packed bf16  (N x 64 -> N x 32) --------
// Register-tiled 64 rows x 32 cols, 4x2 acc/thread.
__global__ __launch_bounds__(256) void gemm2(const float* __restrict__ h,
                                             const float* __restrict__ M2,
                                             unsigned* __restrict__ zbf) {
  __shared__ float sW[H1 * H2];   // 8 KiB, [k][o]
  __shared__ float sX[H1][64];    // 16 KiB, [k][row]
  int tid = threadIdx.x;
  for (int i = tid; i < H1 * H2; i += 256) sW[i] = M2[i];

  int row0 = blockIdx.x * 64;
  int lrow = tid & 63;
  int kg = tid >> 6;  // 0..3, 16 k's each
  bool rv = (row0 + lrow) < N_NODES;
  float4 v[4] = {};
  if (rv) {
    const float* hr = h + (long long)(row0 + lrow) * H1 + kg * 16;
#pragma unroll
    for (int q = 0; q < 4; ++q) v[q] = *reinterpret_cast<const float4*>(hr + q * 4);
  }
#pragma unroll
  for (int q = 0; q < 4; ++q) {
    sX[kg * 16 + q * 4 + 0][lrow] = v[q].x;
    sX[kg * 16 + q * 4 + 1][lrow] = v[q].y;
    sX[kg * 16 + q * 4 + 2][lrow] = v[q].z;
    sX[kg * 16 + q * 4 + 3][lrow] = v[q].w;
  }
  __syncthreads();
  int tr = tid >> 4;  // 0..15, 4 rows each
  int tc = tid & 15;  // 0..15, 2 cols each
  float acc[4][2] = {{0.f}};
#pragma unroll
  for (int k = 0; k < H1; ++k) {
    float4 a = *reinterpret_cast<const float4*>(&sX[k][tr * 4]);
    float2 b = *reinterpret_cast<const float2*>(&sW[k * H2 + tc * 2]);
    acc[0][0] += a.x * b.x; acc[0][1] += a.x * b.y;
    acc[1][0] += a.y * b.x; acc[1][1] += a.y * b.y;
    acc[2][0] += a.z * b.x; acc[2][1] += a.z * b.y;
    acc[3][0] += a.w * b.x; acc[3][1] += a.w * b.y;
  }
#pragma unroll
  for (int i = 0; i < 4; ++i) {
    int row = row0 + tr * 4 + i;
    if (row < N_NODES)
      zbf[(long long)row * 16 + tc] = pack_bf2(acc[i][0], acc[i][1]);
  }
}

// ---- gin3: h2 = relu((1+e2)*z_self + sum z_nb + c2); p=h2.wl, r=h2.wr -----
// 16 lanes per node (lane j = features 2j,2j+1); 16 nodes / block.
__global__ __launch_bounds__(256) void gin3(
    const unsigned* __restrict__ zbf, const int* __restrict__ row_ptr,
    const int2* __restrict__ csr, const float* __restrict__ c2,
    const float* __restrict__ eps2p, const float* __restrict__ wl,
    const float* __restrict__ wr, float* __restrict__ p,
    float* __restrict__ r) {
  int tid = blockIdx.x * 256 + threadIdx.x;
  int node = tid >> 4;
  if (node >= N_NODES) return;
  int j = tid & 15;
  int start = row_ptr[node], end = row_ptr[node + 1];
  float a0 = 0.f, a1 = 0.f;
  int e = start;
  for (; e + 4 <= end; e += 4) {
    int s0 = csr[e + 0].x;
    int s1 = csr[e + 1].x;
    int s2 = csr[e + 2].x;
    int s3 = csr[e + 3].x;
    float2 u0 = unpack_bf2(zbf[(unsigned)s0 * 16 + j]);
    float2 u1 = unpack_bf2(zbf[(unsigned)s1 * 16 + j]);
    float2 u2 = unpack_bf2(zbf[(unsigned)s2 * 16 + j]);
    float2 u3 = unpack_bf2(zbf[(unsigned)s3 * 16 + j]);
    a0 += (u0.x + u1.x) + (u2.x + u3.x);
    a1 += (u0.y + u1.y) + (u2.y + u3.y);
  }
  float2 t0 = make_float2(0.f, 0.f), t1 = make_float2(0.f, 0.f),
         t2 = make_float2(0.f, 0.f);
  if (e + 0 < end) t0 = unpack_bf2(zbf[(unsigned)csr[e + 0].x * 16 + j]);
  if (e + 1 < end) t1 = unpack_bf2(zbf[(unsigned)csr[e + 1].x * 16 + j]);
  if (e + 2 < end) t2 = unpack_bf2(zbf[(unsigned)csr[e + 2].x * 16 + j]);
  a0 += (t0.x + t1.x) + t2.x;
  a1 += (t0.y + t1.y) + t2.y;
  float eps2 = 1.0f + *eps2p;
  float2 self = unpack_bf2(zbf[(unsigned)node * 16 + j]);
  float2 c = *reinterpret_cast<const float2*>(&c2[2 * j]);
  float h0 = fmaxf(eps2 * self.x + a0 + c.x, 0.f);
  float h1 = fmaxf(eps2 * self.y + a1 + c.y, 0.f);
  float2 l = *reinterpret_cast<const float2*>(&wl[2 * j]);
  float2 w = *reinterpret_cast<const float2*>(&wr[2 * j]);
  float pd = h0 * l.x + h1 * l.y;
  float rd = h0 * w.x + h1 * w.y;
#pragma unroll
  for (int m = 8; m >= 1; m >>= 1) {
    pd += __shfl_xor(pd, m, 16);
    rd += __shfl_xor(rd, m, 16);
  }
  if (j == 0) {
    p[node] = pd;
    r[node] = rd;
  }
}

// ---- SAGE: mean of ew*p[src] over in-edges + root path, relu --------------
__global__ __launch_bounds__(256) void sage_out(
    const int* __restrict__ row_ptr, const int2* __restrict__ csr,
    const float* __restrict__ p, const float* __restrict__ r,
    const float* __restrict__ blp, float* __restrict__ out) {
  int idx = blockIdx.x * 256 + threadIdx.x;
  int node = idx >> 4;
  if (node >= N_NODES) return;
  int l = idx & 15;
  int start = row_ptr[node], end = row_ptr[node + 1];
  float acc = 0.f;
  for (int e = start + l; e < end; e += 16) {
    int2 c = csr[e];
    acc += __int_as_float(c.y) * p[c.x];
  }
#pragma unroll
  for (int m = 8; m >= 1; m >>= 1) acc += __shfl_xor(acc, m, 16);
  if (l == 0) {
    float mean = acc / fmaxf((float)(end - start), 1.0f);
    out[node] = fmaxf(mean + blp[0] + r[node], 0.f);
  }
}

extern "C" void kernel_launch(void* const* d_in, const int* in_sizes, int n_in,
                              void* d_out, int out_size, void* d_ws,
                              size_t ws_size, hipStream_t stream) {
  const float* x = (const float*)d_in[0];
  const int* ei = (const int*)d_in[1];
  const float* ea = (const float*)d_in[2];
  const float* w1a = (const float*)d_in[3];
  const float* b1a = (const float*)d_in[4];
  const float* w1b = (const float*)d_in[5];
  const float* b1b = (const float*)d_in[6];
  const float* eps1 = (const float*)d_in[7];
  const float* w2a = (const float*)d_in[8];
  const float* b2a = (const float*)d_in[9];
  const float* w2b = (const float*)d_in[10];
  const float* b2b = (const float*)d_in[11];
  const float* eps2 = (const float*)d_in[12];
  const float* wl = (const float*)d_in[13];
  const float* bl = (const float*)d_in[14];
  const float* wr = (const float*)d_in[15];
  float* out = (float*)d_out;

  // workspace layout (4-byte words; csr kept 8B-aligned)
  float* ws = (float*)d_ws;
  float* M1 = ws;                                   // 8192
  float* c1 = M1 + F_IN * H1;                       // 64
  float* M2 = c1 + H1;                              // 2048
  float* c2 = M2 + H1 * H2;                         // 32
  unsigned* ybf = (unsigned*)(c2 + H2);             // N*32
  float* h = (float*)(ybf + (size_t)N_NODES * 32);  // N*64
  unsigned* zbf = (unsigned*)(h + (size_t)N_NODES * H1);  // N*16
  float* p = (float*)(zbf + (size_t)N_NODES * 16);  // N
  float* r = p + N_NODES;                           // N
  int2* csr = (int2*)(r + N_NODES);                 // E int2
  int* counts = (int*)(csr + N_EDGES);              // N
  int* cursor = counts + N_NODES;                   // N
  int* bsums = cursor + N_NODES;                    // NBLK
  int* boffs = bsums + NBLK;                        // NBLK
  int* row_ptr = boffs + NBLK;                      // N+1

  hipMemsetAsync(counts, 0, sizeof(int) * (size_t)N_NODES, stream);

  prep_and_count<<<PREP_BLOCKS + CNT_BLOCKS, 256, 0, stream>>>(
      w1a, b1a, w1b, b1b, w2a, b2a, w2b, b2b, M1, c1, M2, c2, ei, counts);

  block_sums<<<NBLK, 256, 0, stream>>>(counts, bsums);
  scan_bsums<<<1, 256, 0, stream>>>(bsums, boffs, row_ptr);
  emit_rowptr<<<NBLK, 256, 0, stream>>>(counts, boffs, row_ptr, cursor);
  fill_csr<<<(N_EDGES + 255) / 256, 256, 0, stream>>>(ei, ea, cursor, csr);

  gemm1<<<(N_NODES + 63) / 64, 256, 0, stream>>>(x, M1, ybf);

  agg_h<<<(N_NODES + 7) / 8, 256, 0, stream>>>(ybf, row_ptr, csr, c1, eps1, h);

  gemm2<<<(N_NODES + 63) / 64, 256, 0, stream>>>(h, M2, zbf);

  gin3<<<(N_NODES * 16 + 255) / 256, 256, 0, stream>>>(zbf, row_ptr, csr, c2,
                                                       eps2, wl, wr, p, r);

  sage_out<<<(N_NODES * 16 + 255) / 256, 256, 0, stream>>>(row_ptr, csr, p, r,
                                                           bl, out);
}